// Round 10
// baseline (867.952 us; speedup 1.0000x reference)
//
#include <hip/hip_runtime.h>
#include <hip/hip_bf16.h>

#define B 512
#define L 50
#define H 256
#define GN (B*L)          // 25600 graph nodes
#define GE (GN*12)        // 307200 edges

typedef unsigned short u16;
typedef unsigned int u32;

__device__ __forceinline__ float bf2f(u16 u){ u32 x=((u32)u)<<16; return __uint_as_float(x); }

// dual-dtype loads: float inputs may be bf16 or f32 on device (probe decides)
__device__ __forceinline__ float4 load4(const void* p, size_t idx, int f32){
  if (f32) return *reinterpret_cast<const float4*>(reinterpret_cast<const float*>(p)+idx);
  ushort4 u = *reinterpret_cast<const ushort4*>(reinterpret_cast<const u16*>(p)+idx);
  return make_float4(bf2f(u.x),bf2f(u.y),bf2f(u.z),bf2f(u.w));
}
__device__ __forceinline__ float load1(const void* p, size_t idx, int f32){
  return f32 ? reinterpret_cast<const float*>(p)[idx] : bf2f(reinterpret_cast<const u16*>(p)[idx]);
}
__device__ __forceinline__ float waveSum(float v){
  #pragma unroll
  for (int m=32;m>0;m>>=1) v += __shfl_xor(v, m, 64);
  return v;
}

// --- dtype probe: bf16 data -> all small; f32 reinterpreted as bf16 -> ~half huge/NaN
__global__ void k_probe(const void* emb, int* flag){
  if (threadIdx.x==0 && blockIdx.x==0){
    int big=0;
    const u16* p=(const u16*)emb;
    for (int i=0;i<256;i++){ float v=bf2f(p[i]); if(!(v==v) || fabsf(v)>4.f) big++; }
    *flag = (big>8)?1:0;
  }
}

// hidden[n,:] = item_emb[items[n],:]  (f32 out)
__global__ void k_gather_hidden(const int* items, const void* item_emb, float* hidden, const int* flagp){
  int f32=*flagp;
  int n=blockIdx.x, lane=threadIdx.x;
  int idx=items[n];
  float4 v=load4(item_emb,(size_t)idx*H+lane*4,f32);
  *reinterpret_cast<float4*>(hidden+(size_t)n*H+lane*4)=v;
}

// per-batch: mean_item, mean_cate (gm-weighted), gm sum, mask-len
__global__ void k_means(const int* items, const int* cates, const int* mask, const float* hidden,
                        const void* cate_emb, float* mi, float* mc, float* gms, int* lend, const int* flagp){
  int f32=*flagp;
  int b=blockIdx.x, h=threadIdx.x;
  float si=0.f, sc=0.f, g=0.f; int lm=0;
  for (int l=0;l<L;l++){
    int it=items[b*L+l];
    float gm=(it>0)?1.f:((it<0)?-1.f:0.f);
    si += gm*hidden[((size_t)b*L+l)*H+h];
    int c=cates[b*L+l];
    sc += gm*load1(cate_emb,(size_t)c*H+h,f32);
    g += gm;
    lm += mask[b*L+l];
  }
  mi[(size_t)b*H+h]=si/g; mc[(size_t)b*H+h]=sc/g;
  if (h==0){ gms[b]=g; lend[b]=lm; }
}

// seq_hidden = hidden[b,alias] + pos_emb[pidx] + len_emb[len]
__global__ void k_seq(const int* alias_, const int* mask, const float* hidden,
                      const void* pos_emb, const void* len_emb, const int* lend, float* seqh, const int* flagp){
  int f32=*flagp;
  int r=blockIdx.x, lane=threadIdx.x;
  int b=r/L, l=r%L;
  int a=alias_[r];
  int ld=lend[b];
  int m=mask[r];
  int pidx=(ld-1-l)*m;
  if (pidx<0) pidx+=L;               // jnp negative-index wrap
  float4 hv=*reinterpret_cast<const float4*>(hidden+((size_t)b*L+a)*H+lane*4);
  float4 pv=load4(pos_emb,(size_t)pidx*H+lane*4,f32);
  float4 lv=load4(len_emb,(size_t)ld*H+lane*4,f32);
  float4 o=make_float4(hv.x+pv.x+lv.x, hv.y+pv.y+lv.y, hv.z+pv.z+lv.z, hv.w+pv.w+lv.w);
  *reinterpret_cast<float4*>(seqh+(size_t)r*H+lane*4)=o;
}

// ht[b,:] = x[b, lend-1, :]
__global__ void k_ht(const float* x, const int* lend, float* ht){
  int b=blockIdx.x, h=threadIdx.x;
  int last=lend[b]-1; if(last<0) last+=L;
  ht[(size_t)b*H+h]=x[((size_t)b*L+last)*H+h];
}

// C[M,Nc] = A(f32)[M,K] @ W(bf16|f32)[K,Nc]  (+bias)(+=C)
__global__ __launch_bounds__(256) void k_gemm(const float* A, const void* W, size_t wOff,
                                              float* C, const void* bias, size_t bOff,
                                              int M, int Nc, int K, int accFlag, const int* flagp){
  int f32=*flagp;
  __shared__ float At[16][68];   // A^T tile, padded for alignment
  __shared__ float Ws[16][64];
  int bm=blockIdx.x*64, bn=blockIdx.y*64;
  int t=threadIdx.x;
  int tx=t&15, ty=t>>4;
  float c[4][4]={};
  int r=t>>2, kq=(t&3)<<2;
  int kk=t>>4, nq=(t&15)<<2;
  for (int k0=0;k0<K;k0+=16){
    float4 av=*reinterpret_cast<const float4*>(A+(size_t)(bm+r)*K+(k0+kq));
    At[kq+0][r]=av.x; At[kq+1][r]=av.y; At[kq+2][r]=av.z; At[kq+3][r]=av.w;
    float4 wv=load4(W,wOff+(size_t)(k0+kk)*Nc+(bn+nq),f32);
    Ws[kk][nq+0]=wv.x; Ws[kk][nq+1]=wv.y; Ws[kk][nq+2]=wv.z; Ws[kk][nq+3]=wv.w;
    __syncthreads();
    #pragma unroll
    for (int q=0;q<16;q++){
      float4 a4=*reinterpret_cast<const float4*>(&At[q][ty<<2]);
      float4 w4=*reinterpret_cast<const float4*>(&Ws[q][tx<<2]);
      float aa[4]={a4.x,a4.y,a4.z,a4.w};
      float ww[4]={w4.x,w4.y,w4.z,w4.w};
      #pragma unroll
      for (int i=0;i<4;i++)
        #pragma unroll
        for (int j=0;j<4;j++) c[i][j]=fmaf(aa[i],ww[j],c[i][j]);
    }
    __syncthreads();
  }
  #pragma unroll
  for (int i=0;i<4;i++){
    size_t row=(size_t)(bm+(ty<<2)+i);
    #pragma unroll
    for (int j=0;j<4;j++){
      int col=bn+(tx<<2)+j;
      float v=c[i][j];
      if (bias) v+=load1(bias,bOff+col,f32);
      if (accFlag) v+=C[row*Nc+col];
      C[row*Nc+col]=v;
    }
  }
}

// alpha[r] = sigmoid(qb[b]+q3[r]+sum(bias0..3)) . w5   (wave per row)
__global__ void k_alpha(const float* qb, const float* q3, const void* seb, size_t bOff,
                        const void* w5, size_t wOff, float* alpha, const int* flagp){
  int f32=*flagp;
  int gid=blockIdx.x*blockDim.x+threadIdx.x;
  int wid=gid>>6, lane=gid&63;
  if (wid>=GN) return;
  int b=wid/L;
  float4 qv=*reinterpret_cast<const float4*>(qb+(size_t)b*H+lane*4);
  float4 q3v=*reinterpret_cast<const float4*>(q3+(size_t)wid*H+lane*4);
  float bs0=0.f,bs1=0.f,bs2=0.f,bs3=0.f;
  #pragma unroll
  for (int j=0;j<4;j++){
    float4 bv=load4(seb,bOff+(size_t)j*H+lane*4,f32);
    bs0+=bv.x; bs1+=bv.y; bs2+=bv.z; bs3+=bv.w;
  }
  float4 wv=load4(w5,wOff+(size_t)lane*4,f32);
  float part=0.f;
  float x0=qv.x+q3v.x+bs0; part+=wv.x/(1.f+expf(-x0));
  float x1=qv.y+q3v.y+bs1; part+=wv.y/(1.f+expf(-x1));
  float x2=qv.z+q3v.z+bs2; part+=wv.z/(1.f+expf(-x2));
  float x3=qv.w+q3v.w+bs3; part+=wv.w/(1.f+expf(-x3));
  part=waveSum(part);
  if (lane==0) alpha[wid]=part;
}

// a[b,h]=sum_l alpha*seq*mask ; cat=[a|ht]
__global__ void k_pool(const float* alpha, const float* seqh, const int* mask, const float* ht, float* cat){
  int b=blockIdx.x, h=threadIdx.x;
  float a=0.f;
  for (int l=0;l<L;l++)
    a += alpha[b*L+l]*seqh[((size_t)b*L+l)*H+h]*(float)mask[b*L+l];
  cat[(size_t)b*2*H+h]=a;
  cat[(size_t)b*2*H+H+h]=ht[(size_t)b*H+h];
}

__global__ void k_count(const int* dst, int* cnt){
  int e=blockIdx.x*blockDim.x+threadIdx.x;
  if (e<GE) atomicAdd(&cnt[dst[e]],1);
}

// exclusive scan of cnt[25600] -> rowp[25601], one block of 1024 threads x 25 elems
__global__ void k_scan(const int* cnt, int* rowp){
  __shared__ int s[1024];
  int t=threadIdx.x;
  int base=t*25;
  int local[25]; int sum=0;
  #pragma unroll
  for (int i=0;i<25;i++){ local[i]=sum; sum+=cnt[base+i]; }
  s[t]=sum; __syncthreads();
  for (int off=1;off<1024;off<<=1){
    int v=(t>=off)?s[t-off]:0; __syncthreads();
    s[t]+=v; __syncthreads();
  }
  int excl=s[t]-sum;
  #pragma unroll
  for (int i=0;i<25;i++) rowp[base+i]=excl+local[i];
  if (t==1023) rowp[GN]=s[1023];
}

__global__ void k_fill(const int* dst, const int* rowp, int* cnt, int* eord){
  int e=blockIdx.x*blockDim.x+threadIdx.x;
  if (e<GE){ int d=dst[e]; int pos=rowp[d]+atomicAdd(&cnt[d],1); eord[pos]=e; }
}

// one wave per node: online-softmax GAT aggregation (exact up to fp rounding)
__global__ void k_node(const float* hg, const int* src, const int* etype, const void* eattr,
                       const void* rel, const int* rowp, const int* eord, float* out, const int* flagp){
  int f32=*flagp;
  int gid=blockIdx.x*blockDim.x+threadIdx.x;
  int n=gid>>6, lane=gid&63;
  if (n>=GN) return;
  float4 hn=*reinterpret_cast<const float4*>(hg+(size_t)n*H+lane*4);
  int b0=rowp[n], b1=rowp[n+1];
  float mx=-INFINITY, den=0.f;
  float4 acc=make_float4(0.f,0.f,0.f,0.f);
  for (int i=b0;i<b1;i++){
    int e=eord[i]; int s=src[e]; int ty=etype[e];
    float4 hs=*reinterpret_cast<const float4*>(hg+(size_t)s*H+lane*4);
    float4 rv=load4(rel,(size_t)ty*H+lane*4,f32);
    float4 m4=make_float4(hs.x+rv.x,hs.y+rv.y,hs.z+rv.z,hs.w+rv.w);
    float p=hn.x*m4.x+hn.y*m4.y+hn.z*m4.z+hn.w*m4.w;
    p=waveSum(p)*(1.f/16.f);
    float lg=(p>0.f?p:0.2f*p)+load1(eattr,e,f32);
    if (lg>mx){
      float sc=expf(mx-lg);      // first iter: exp(-inf)=0
      den*=sc; acc.x*=sc; acc.y*=sc; acc.z*=sc; acc.w*=sc;
      mx=lg;
    }
    float ex=expf(lg-mx);
    den+=ex;
    acc.x+=ex*m4.x; acc.y+=ex*m4.y; acc.z+=ex*m4.z; acc.w+=ex*m4.w;
  }
  float inv=1.f/(den+1e-12f);
  float4 o=make_float4(acc.x*inv,acc.y*inv,acc.z*inv,acc.w*inv);
  *reinterpret_cast<float4*>(out+(size_t)n*H+lane*4)=o;
}

// s_node[b,h] = sum_l gm*graph / gms
__global__ void k_avepool(const float* x, const int* items, const float* gms, float* out){
  int b=blockIdx.x, h=threadIdx.x;
  float s=0.f;
  for (int l=0;l<L;l++){
    int it=items[b*L+l];
    float gm=(it>0)?1.f:((it<0)?-1.f:0.f);
    s += gm*x[((size_t)b*L+l)*H+h];
  }
  out[(size_t)b*H+h]=s/gms[b];
}

__global__ void k_gseq(const int* alias_, const float* graph, float* gseq){
  int r=blockIdx.x, lane=threadIdx.x;
  int b=r/L;
  int a=alias_[r];
  float4 v=*reinterpret_cast<const float4*>(graph+((size_t)b*L+a)*H+lane*4);
  *reinterpret_cast<float4*>(gseq+(size_t)r*H+lane*4)=v;
}

// out = layer_norm(sl+sg): center, then /sqrt(sum(x^2)); FLOAT32 out
// (fix R9: d_out is float32 — inputs proven f32 by npz size arithmetic; harness
//  rule "reference output dtype f32 -> float*". Writing bf16 here produced the
//  uncorrelated 0.274 absmax signature: interleaved-bf16-as-f32 + zero tail.)
__global__ void k_final(const float* sl, const float* sg, float* out){
  __shared__ float red[8];
  int b=blockIdx.x, h=threadIdx.x;
  int wid=h>>6, lane=h&63;
  float v=sl[(size_t)b*H+h]+sg[(size_t)b*H+h];
  float s=waveSum(v);
  if (lane==0) red[wid]=s;
  __syncthreads();
  float tot=red[0]+red[1]+red[2]+red[3];
  float x=v-tot/(float)H;
  float s2=waveSum(x*x);
  __syncthreads();
  if (lane==0) red[wid]=s2;
  __syncthreads();
  float ss=red[0]+red[1]+red[2]+red[3];
  out[(size_t)b*H+h]=x/sqrtf(ss);
}

extern "C" void kernel_launch(void* const* d_in, const int* in_sizes, int n_in,
                              void* d_out, int out_size, void* d_ws, size_t ws_size,
                              hipStream_t stream){
  (void)in_sizes; (void)n_in; (void)out_size; (void)ws_size;
  const int* alias_=(const int*)d_in[0];
  const int* items =(const int*)d_in[1];
  const int* mask  =(const int*)d_in[2];
  const int* cates =(const int*)d_in[3];
  const int* eind  =(const int*)d_in[4];
  const int* etype =(const int*)d_in[5];
  const void* eattr   =d_in[6];
  const void* item_emb=d_in[7];
  const void* cate_emb=d_in[8];
  const void* pos_emb =d_in[9];
  const void* len_emb =d_in[10];
  const void* rel_emb =d_in[11];
  const void* se_W    =d_in[12];
  const void* se_b    =d_in[13];
  const void* se_w5   =d_in[14];
  const void* se_Wt   =d_in[15];
  const void* se_bt   =d_in[16];
  const void* gat_W   =d_in[17];
  const int* esrc=eind; const int* edst=eind+GE;

  char* w=(char*)d_ws;
  auto carve=[&](size_t nbytes)->char*{ char* p=w; w += (nbytes+255)&~(size_t)255; return p; };
  float* buf1 =(float*)carve((size_t)GN*H*4);   // hidden, later graph_emb
  float* buf2 =(float*)carve((size_t)GN*H*4);   // seq_hidden, later g_seq
  float* hgat =(float*)carve((size_t)GN*H*4);
  float* q3   =(float*)carve((size_t)GN*H*4);
  float* alphaB=(float*)carve((size_t)GN*4);
  float* qb   =(float*)carve((size_t)B*H*4);
  float* mi   =(float*)carve((size_t)B*H*4);
  float* mc   =(float*)carve((size_t)B*H*4);
  float* sn   =(float*)carve((size_t)B*H*4);
  float* gms  =(float*)carve((size_t)B*4);
  int*   lend =(int*)  carve((size_t)B*4);
  float* htb  =(float*)carve((size_t)B*H*4);
  float* htg  =(float*)carve((size_t)B*H*4);
  float* catb =(float*)carve((size_t)B*2*H*4);
  float* sl   =(float*)carve((size_t)B*H*4);
  float* sg   =(float*)carve((size_t)B*H*4);
  int*   cnt  =(int*)  carve((size_t)GN*4);
  int*   rowp =(int*)  carve((size_t)(GN+1)*4);
  int*   eord =(int*)  carve((size_t)GE*4);
  int*   flag =(int*)  carve(256);

  dim3 blk(256), gBig(GN/64,H/64), gSm(B/64,H/64);

  k_probe<<<1,64,0,stream>>>(item_emb, flag);
  k_gather_hidden<<<GN,64,0,stream>>>(items, item_emb, buf1, flag);
  k_means<<<B,256,0,stream>>>(items,cates,mask,buf1,cate_emb,mi,mc,gms,lend,flag);
  k_seq<<<GN,64,0,stream>>>(alias_,mask,buf1,pos_emb,len_emb,lend,buf2,flag);
  k_ht<<<B,256,0,stream>>>(buf2,lend,htb);

  // GAT projection (uses hidden before buf1 is reused)
  k_gemm<<<gBig,blk,0,stream>>>(buf1, gat_W, 0, hgat, nullptr,0, GN,H,H, 0, flag);

  // local session encoder
  k_gemm<<<gBig,blk,0,stream>>>(buf2, se_W, (size_t)2*H*H, q3, nullptr,0, GN,H,H, 0, flag);
  k_gemm<<<gSm,blk,0,stream>>>(htb, se_W, 0,             qb, nullptr,0, B,H,H, 0, flag);
  k_gemm<<<gSm,blk,0,stream>>>(mi,  se_W, (size_t)1*H*H, qb, nullptr,0, B,H,H, 1, flag);
  k_gemm<<<gSm,blk,0,stream>>>(mc,  se_W, (size_t)3*H*H, qb, nullptr,0, B,H,H, 1, flag);
  k_alpha<<<GN/4,256,0,stream>>>(qb,q3,se_b,0,se_w5,0,alphaB,flag);
  k_pool<<<B,256,0,stream>>>(alphaB,buf2,mask,htb,catb);
  k_gemm<<<gSm,blk,0,stream>>>(catb, se_Wt, 0, sl, se_bt, 0, B,H,2*H, 0, flag);

  // GAT: CSR build + per-node online-softmax aggregation
  (void)hipMemsetAsync(cnt,0,(size_t)GN*4,stream);
  k_count<<<GE/256,256,0,stream>>>(edst,cnt);
  k_scan<<<1,1024,0,stream>>>(cnt,rowp);
  (void)hipMemsetAsync(cnt,0,(size_t)GN*4,stream);
  k_fill<<<GE/256,256,0,stream>>>(edst,rowp,cnt,eord);
  k_node<<<GN/4,256,0,stream>>>(hgat,esrc,etype,eattr,rel_emb,rowp,eord,buf1,flag);

  // global session encoder
  k_avepool<<<B,256,0,stream>>>(buf1,items,gms,sn);
  k_gseq<<<GN,64,0,stream>>>(alias_,buf1,buf2);
  k_ht<<<B,256,0,stream>>>(buf2,lend,htg);
  k_gemm<<<gBig,blk,0,stream>>>(buf2, se_W, (size_t)6*H*H, q3, nullptr,0, GN,H,H, 0, flag);
  k_gemm<<<gSm,blk,0,stream>>>(htg, se_W, (size_t)4*H*H, qb, nullptr,0, B,H,H, 0, flag);
  k_gemm<<<gSm,blk,0,stream>>>(mi,  se_W, (size_t)5*H*H, qb, nullptr,0, B,H,H, 1, flag);
  k_gemm<<<gSm,blk,0,stream>>>(sn,  se_W, (size_t)7*H*H, qb, nullptr,0, B,H,H, 1, flag);
  k_alpha<<<GN/4,256,0,stream>>>(qb,q3,se_b,(size_t)4*H,se_w5,(size_t)H,alphaB,flag);
  k_pool<<<B,256,0,stream>>>(alphaB,buf2,mask,htg,catb);
  k_gemm<<<gSm,blk,0,stream>>>(catb, se_Wt, (size_t)2*H*H, sg, se_bt, (size_t)H, B,H,2*H, 0, flag);

  k_final<<<B,256,0,stream>>>(sl,sg,(float*)d_out);
}

// Round 11
// 817.969 us; speedup vs baseline: 1.0611x; 1.0611x over previous
//
#include <hip/hip_runtime.h>

#define B 512
#define L 50
#define H 256
#define GN (B*L)          // 25600 graph nodes
#define GE (GN*12)        // 307200 edges

__device__ __forceinline__ float waveSum(float v){
  #pragma unroll
  for (int m=32;m>0;m>>=1) v += __shfl_xor(v, m, 64);
  return v;
}
__device__ __forceinline__ float sigm(float x){ return 1.f/(1.f+expf(-x)); }

// fused: hidden[n,:] = item_emb[items[n],:]; mi/mc = gm-weighted means; gms, lend
__global__ void k_gather_means(const int* items, const int* cates, const int* mask,
                               const float* item_emb, const float* cate_emb,
                               float* hidden, float* mi, float* mc, float* gms, int* lend){
  int b=blockIdx.x, h=threadIdx.x;
  float si=0.f, sc=0.f, g=0.f; int lm=0;
  for (int l=0;l<L;l++){
    int it=items[b*L+l];
    float gm=(it>0)?1.f:((it<0)?-1.f:0.f);
    float v=item_emb[(size_t)it*H+h];
    hidden[((size_t)b*L+l)*H+h]=v;
    si += gm*v;
    sc += gm*cate_emb[(size_t)cates[b*L+l]*H+h];
    g += gm;
    lm += mask[b*L+l];
  }
  mi[(size_t)b*H+h]=si/g; mc[(size_t)b*H+h]=sc/g;
  if (h==0){ gms[b]=g; lend[b]=lm; }
}

// seq_hidden = hidden[b,alias] + pos_emb[pidx] + len_emb[len]; also writes ht row (l==last)
__global__ void k_seq(const int* alias_, const int* mask, const float* hidden,
                      const float* pos_emb, const float* len_emb, const int* lend,
                      float* seqh, float* ht){
  int r=blockIdx.x, lane=threadIdx.x;
  int b=r/L, l=r%L;
  int a=alias_[r];
  int ld=lend[b];
  int m=mask[r];
  int pidx=(ld-1-l)*m;
  if (pidx<0) pidx+=L;               // jnp negative-index wrap
  float4 hv=*reinterpret_cast<const float4*>(hidden+((size_t)b*L+a)*H+lane*4);
  float4 pv=*reinterpret_cast<const float4*>(pos_emb+(size_t)pidx*H+lane*4);
  float4 lv=*reinterpret_cast<const float4*>(len_emb+(size_t)ld*H+lane*4);
  float4 o=make_float4(hv.x+pv.x+lv.x, hv.y+pv.y+lv.y, hv.z+pv.z+lv.z, hv.w+pv.w+lv.w);
  *reinterpret_cast<float4*>(seqh+(size_t)r*H+lane*4)=o;
  if (l == (ld+L-1)%L)
    *reinterpret_cast<float4*>(ht+(size_t)b*H+lane*4)=o;
}

// C[M,Nc] = A[M,K] @ W[K,Nc] (+bias)
__global__ __launch_bounds__(256) void k_gemm(const float* A, const float* W, size_t wOff,
                                              float* C, const float* bias, size_t bOff,
                                              int M, int Nc, int K){
  __shared__ float At[16][68];
  __shared__ float Ws[16][64];
  int bm=blockIdx.x*64, bn=blockIdx.y*64;
  int t=threadIdx.x;
  int tx=t&15, ty=t>>4;
  float c[4][4]={};
  int r=t>>2, kq=(t&3)<<2;
  int kk=t>>4, nq=(t&15)<<2;
  for (int k0=0;k0<K;k0+=16){
    float4 av=*reinterpret_cast<const float4*>(A+(size_t)(bm+r)*K+(k0+kq));
    At[kq+0][r]=av.x; At[kq+1][r]=av.y; At[kq+2][r]=av.z; At[kq+3][r]=av.w;
    float4 wv=*reinterpret_cast<const float4*>(W+wOff+(size_t)(k0+kk)*Nc+(bn+nq));
    Ws[kk][nq+0]=wv.x; Ws[kk][nq+1]=wv.y; Ws[kk][nq+2]=wv.z; Ws[kk][nq+3]=wv.w;
    __syncthreads();
    #pragma unroll
    for (int q=0;q<16;q++){
      float4 a4=*reinterpret_cast<const float4*>(&At[q][ty<<2]);
      float4 w4=*reinterpret_cast<const float4*>(&Ws[q][tx<<2]);
      float aa[4]={a4.x,a4.y,a4.z,a4.w};
      float ww[4]={w4.x,w4.y,w4.z,w4.w};
      #pragma unroll
      for (int i=0;i<4;i++)
        #pragma unroll
        for (int j=0;j<4;j++) c[i][j]=fmaf(aa[i],ww[j],c[i][j]);
    }
    __syncthreads();
  }
  #pragma unroll
  for (int i=0;i<4;i++){
    size_t row=(size_t)(bm+(ty<<2)+i);
    #pragma unroll
    for (int j=0;j<4;j++){
      int col=bn+(tx<<2)+j;
      float v=c[i][j];
      if (bias) v+=bias[bOff+col];
      C[row*Nc+col]=v;
    }
  }
}

// qb = A0@W[i0] + A1@W[i1] + A2@W[i2] + sum(4 bias rows); M=512, Nc=256, K=256 per source
__global__ __launch_bounds__(256) void k_qb3(const float* A0, const float* A1, const float* A2,
                                             const float* W, size_t wBase,
                                             const float* seb, size_t bOff, float* C){
  __shared__ float At[16][68];
  __shared__ float Ws[16][64];
  int bm=blockIdx.x*64, bn=blockIdx.y*64;
  int t=threadIdx.x;
  int tx=t&15, ty=t>>4;
  float c[4][4]={};
  int r=t>>2, kq=(t&3)<<2;
  int kk=t>>4, nq=(t&15)<<2;
  const float* As[3]={A0,A1,A2};
  const int widx[3]={0,1,3};     // linears one, two, four
  for (int src=0;src<3;src++){
    const float* A=As[src];
    size_t wOff=wBase+(size_t)widx[src]*H*H;
    for (int k0=0;k0<H;k0+=16){
      float4 av=*reinterpret_cast<const float4*>(A+(size_t)(bm+r)*H+(k0+kq));
      At[kq+0][r]=av.x; At[kq+1][r]=av.y; At[kq+2][r]=av.z; At[kq+3][r]=av.w;
      float4 wv=*reinterpret_cast<const float4*>(W+wOff+(size_t)(k0+kk)*H+(bn+nq));
      Ws[kk][nq+0]=wv.x; Ws[kk][nq+1]=wv.y; Ws[kk][nq+2]=wv.z; Ws[kk][nq+3]=wv.w;
      __syncthreads();
      #pragma unroll
      for (int q=0;q<16;q++){
        float4 a4=*reinterpret_cast<const float4*>(&At[q][ty<<2]);
        float4 w4=*reinterpret_cast<const float4*>(&Ws[q][tx<<2]);
        float aa[4]={a4.x,a4.y,a4.z,a4.w};
        float ww[4]={w4.x,w4.y,w4.z,w4.w};
        #pragma unroll
        for (int i=0;i<4;i++)
          #pragma unroll
          for (int j=0;j<4;j++) c[i][j]=fmaf(aa[i],ww[j],c[i][j]);
      }
      __syncthreads();
    }
  }
  #pragma unroll
  for (int i=0;i<4;i++){
    size_t row=(size_t)(bm+(ty<<2)+i);
    #pragma unroll
    for (int j=0;j<4;j++){
      int col=bn+(tx<<2)+j;
      float v=c[i][j]
        + seb[bOff+0*H+col] + seb[bOff+1*H+col]
        + seb[bOff+2*H+col] + seb[bOff+3*H+col];
      C[row*H+col]=v;
    }
  }
}

// alpha[r] = sigmoid(qb[b]+q3[r]) . w5   (biases pre-summed into qb; wave per row)
__global__ void k_alpha(const float* qb, const float* q3, const float* w5, size_t wOff,
                        float* alpha){
  int gid=blockIdx.x*blockDim.x+threadIdx.x;
  int wid=gid>>6, lane=gid&63;
  if (wid>=GN) return;
  int b=wid/L;
  float4 qv=*reinterpret_cast<const float4*>(qb+(size_t)b*H+lane*4);
  float4 q3v=*reinterpret_cast<const float4*>(q3+(size_t)wid*H+lane*4);
  float4 wv=*reinterpret_cast<const float4*>(w5+wOff+(size_t)lane*4);
  float part = wv.x*sigm(qv.x+q3v.x) + wv.y*sigm(qv.y+q3v.y)
             + wv.z*sigm(qv.z+q3v.z) + wv.w*sigm(qv.w+q3v.w);
  part=waveSum(part);
  if (lane==0) alpha[wid]=part;
}

// a[b,h]=sum_l alpha*seq*mask ; cat=[a|ht]
__global__ void k_pool(const float* alpha, const float* seqh, const int* mask, const float* ht, float* cat){
  int b=blockIdx.x, h=threadIdx.x;
  float a=0.f;
  for (int l=0;l<L;l++)
    a += alpha[b*L+l]*seqh[((size_t)b*L+l)*H+h]*(float)mask[b*L+l];
  cat[(size_t)b*2*H+h]=a;
  cat[(size_t)b*2*H+H+h]=ht[(size_t)b*H+h];
}

__global__ void k_count(const int* dst, int* cnt){
  int e=blockIdx.x*blockDim.x+threadIdx.x;
  if (e<GE) atomicAdd(&cnt[dst[e]],1);
}

// exclusive scan of cnt[25600] -> rowp[25601]
__global__ void k_scan(const int* cnt, int* rowp){
  __shared__ int s[1024];
  int t=threadIdx.x;
  int base=t*25;
  int local[25]; int sum=0;
  #pragma unroll
  for (int i=0;i<25;i++){ local[i]=sum; sum+=cnt[base+i]; }
  s[t]=sum; __syncthreads();
  for (int off=1;off<1024;off<<=1){
    int v=(t>=off)?s[t-off]:0; __syncthreads();
    s[t]+=v; __syncthreads();
  }
  int excl=s[t]-sum;
  #pragma unroll
  for (int i=0;i<25;i++) rowp[base+i]=excl+local[i];
  if (t==1023) rowp[GN]=s[1023];
}

__global__ void k_fill(const int* dst, const int* rowp, int* cnt, int* eord){
  int e=blockIdx.x*blockDim.x+threadIdx.x;
  if (e<GE){ int d=dst[e]; int pos=rowp[d]+atomicAdd(&cnt[d],1); eord[pos]=e; }
}

// one wave per node: online-softmax GAT aggregation
__global__ void k_node(const float* hg, const int* src, const int* etype, const float* eattr,
                       const float* rel, const int* rowp, const int* eord, float* out){
  int gid=blockIdx.x*blockDim.x+threadIdx.x;
  int n=gid>>6, lane=gid&63;
  if (n>=GN) return;
  float4 hn=*reinterpret_cast<const float4*>(hg+(size_t)n*H+lane*4);
  int b0=rowp[n], b1=rowp[n+1];
  float mx=-INFINITY, den=0.f;
  float4 acc=make_float4(0.f,0.f,0.f,0.f);
  for (int i=b0;i<b1;i++){
    int e=eord[i]; int s=src[e]; int ty=etype[e];
    float4 hs=*reinterpret_cast<const float4*>(hg+(size_t)s*H+lane*4);
    float4 rv=*reinterpret_cast<const float4*>(rel+(size_t)ty*H+lane*4);
    float4 m4=make_float4(hs.x+rv.x,hs.y+rv.y,hs.z+rv.z,hs.w+rv.w);
    float p=hn.x*m4.x+hn.y*m4.y+hn.z*m4.z+hn.w*m4.w;
    p=waveSum(p)*(1.f/16.f);
    float lg=(p>0.f?p:0.2f*p)+eattr[e];
    if (lg>mx){
      float sc=expf(mx-lg);      // first iter: exp(-inf)=0
      den*=sc; acc.x*=sc; acc.y*=sc; acc.z*=sc; acc.w*=sc;
      mx=lg;
    }
    float ex=expf(lg-mx);
    den+=ex;
    acc.x+=ex*m4.x; acc.y+=ex*m4.y; acc.z+=ex*m4.z; acc.w+=ex*m4.w;
  }
  float inv=1.f/(den+1e-12f);
  float4 o=make_float4(acc.x*inv,acc.y*inv,acc.z*inv,acc.w*inv);
  *reinterpret_cast<float4*>(out+(size_t)n*H+lane*4)=o;
}

// s_node[b,h] = sum_l gm*graph / gms
__global__ void k_avepool(const float* x, const int* items, const float* gms, float* out){
  int b=blockIdx.x, h=threadIdx.x;
  float s=0.f;
  for (int l=0;l<L;l++){
    int it=items[b*L+l];
    float gm=(it>0)?1.f:((it<0)?-1.f:0.f);
    s += gm*x[((size_t)b*L+l)*H+h];
  }
  out[(size_t)b*H+h]=s/gms[b];
}

// g_seq gather; also writes ht_g row (l==last)
__global__ void k_gseq(const int* alias_, const float* graph, const int* lend, float* gseq, float* ht){
  int r=blockIdx.x, lane=threadIdx.x;
  int b=r/L, l=r%L;
  int a=alias_[r];
  float4 v=*reinterpret_cast<const float4*>(graph+((size_t)b*L+a)*H+lane*4);
  *reinterpret_cast<float4*>(gseq+(size_t)r*H+lane*4)=v;
  int ld=lend[b];
  if (l == (ld+L-1)%L)
    *reinterpret_cast<float4*>(ht+(size_t)b*H+lane*4)=v;
}

// out = layer_norm(sl+sg): center, then /sqrt(sum(x^2)); f32 out
__global__ void k_final(const float* sl, const float* sg, float* out){
  __shared__ float red[8];
  int b=blockIdx.x, h=threadIdx.x;
  int wid=h>>6, lane=h&63;
  float v=sl[(size_t)b*H+h]+sg[(size_t)b*H+h];
  float s=waveSum(v);
  if (lane==0) red[wid]=s;
  __syncthreads();
  float tot=red[0]+red[1]+red[2]+red[3];
  float x=v-tot/(float)H;
  float s2=waveSum(x*x);
  __syncthreads();
  if (lane==0) red[wid]=s2;
  __syncthreads();
  float ss=red[0]+red[1]+red[2]+red[3];
  out[(size_t)b*H+h]=x/sqrtf(ss);
}

extern "C" void kernel_launch(void* const* d_in, const int* in_sizes, int n_in,
                              void* d_out, int out_size, void* d_ws, size_t ws_size,
                              hipStream_t stream){
  (void)in_sizes; (void)n_in; (void)out_size; (void)ws_size;
  const int* alias_=(const int*)d_in[0];
  const int* items =(const int*)d_in[1];
  const int* mask  =(const int*)d_in[2];
  const int* cates =(const int*)d_in[3];
  const int* eind  =(const int*)d_in[4];
  const int* etype =(const int*)d_in[5];
  const float* eattr   =(const float*)d_in[6];
  const float* item_emb=(const float*)d_in[7];
  const float* cate_emb=(const float*)d_in[8];
  const float* pos_emb =(const float*)d_in[9];
  const float* len_emb =(const float*)d_in[10];
  const float* rel_emb =(const float*)d_in[11];
  const float* se_W    =(const float*)d_in[12];
  const float* se_b    =(const float*)d_in[13];
  const float* se_w5   =(const float*)d_in[14];
  const float* se_Wt   =(const float*)d_in[15];
  const float* se_bt   =(const float*)d_in[16];
  const float* gat_W   =(const float*)d_in[17];
  const int* esrc=eind; const int* edst=eind+GE;

  char* w=(char*)d_ws;
  auto carve=[&](size_t nbytes)->char*{ char* p=w; w += (nbytes+255)&~(size_t)255; return p; };
  float* buf1 =(float*)carve((size_t)GN*H*4);   // hidden, later graph_emb
  float* buf2 =(float*)carve((size_t)GN*H*4);   // seq_hidden, later g_seq
  float* hgat =(float*)carve((size_t)GN*H*4);
  float* q3   =(float*)carve((size_t)GN*H*4);
  float* alphaB=(float*)carve((size_t)GN*4);
  float* qb   =(float*)carve((size_t)B*H*4);
  float* mi   =(float*)carve((size_t)B*H*4);
  float* mc   =(float*)carve((size_t)B*H*4);
  float* sn   =(float*)carve((size_t)B*H*4);
  float* gms  =(float*)carve((size_t)B*4);
  int*   lend =(int*)  carve((size_t)B*4);
  float* htb  =(float*)carve((size_t)B*H*4);
  float* htg  =(float*)carve((size_t)B*H*4);
  float* catb =(float*)carve((size_t)B*2*H*4);
  float* sl   =(float*)carve((size_t)B*H*4);
  float* sg   =(float*)carve((size_t)B*H*4);
  int*   cnt  =(int*)  carve((size_t)GN*4);
  int*   rowp =(int*)  carve((size_t)(GN+1)*4);
  int*   eord =(int*)  carve((size_t)GE*4);

  dim3 blk(256), gBig(GN/64,H/64), gSm(B/64,H/64);

  k_gather_means<<<B,256,0,stream>>>(items,cates,mask,item_emb,cate_emb,buf1,mi,mc,gms,lend);
  k_seq<<<GN,64,0,stream>>>(alias_,mask,buf1,pos_emb,len_emb,lend,buf2,htb);

  // GAT projection (uses hidden before buf1 is reused)
  k_gemm<<<gBig,blk,0,stream>>>(buf1, gat_W, 0, hgat, nullptr,0, GN,H,H);

  // local session encoder
  k_gemm<<<gBig,blk,0,stream>>>(buf2, se_W, (size_t)2*H*H, q3, nullptr,0, GN,H,H);
  k_qb3<<<gSm,blk,0,stream>>>(htb, mi, mc, se_W, 0, se_b, 0, qb);
  k_alpha<<<GN/4,256,0,stream>>>(qb,q3,se_w5,0,alphaB);
  k_pool<<<B,256,0,stream>>>(alphaB,buf2,mask,htb,catb);
  k_gemm<<<gSm,blk,0,stream>>>(catb, se_Wt, 0, sl, se_bt, 0, B,H,2*H);

  // GAT: CSR build + per-node online-softmax aggregation
  (void)hipMemsetAsync(cnt,0,(size_t)GN*4,stream);
  k_count<<<GE/256,256,0,stream>>>(edst,cnt);
  k_scan<<<1,1024,0,stream>>>(cnt,rowp);
  (void)hipMemsetAsync(cnt,0,(size_t)GN*4,stream);
  k_fill<<<GE/256,256,0,stream>>>(edst,rowp,cnt,eord);
  k_node<<<GN/4,256,0,stream>>>(hgat,esrc,etype,eattr,rel_emb,rowp,eord,buf1);

  // global session encoder
  k_avepool<<<B,256,0,stream>>>(buf1,items,gms,sn);
  k_gseq<<<GN,64,0,stream>>>(alias_,buf1,lend,buf2,htg);
  k_gemm<<<gBig,blk,0,stream>>>(buf2, se_W, (size_t)6*H*H, q3, nullptr,0, GN,H,H);
  k_qb3<<<gSm,blk,0,stream>>>(htg, mi, sn, se_W, (size_t)4*H*H, se_b, (size_t)4*H, qb);
  k_alpha<<<GN/4,256,0,stream>>>(qb,q3,se_w5,(size_t)H,alphaB);
  k_pool<<<B,256,0,stream>>>(alphaB,buf2,mask,htg,catb);
  k_gemm<<<gSm,blk,0,stream>>>(catb, se_Wt, (size_t)2*H*H, sg, se_bt, (size_t)H, B,H,2*H);

  k_final<<<B,256,0,stream>>>(sl,sg,(float*)d_out);
}

// Round 14
// 707.889 us; speedup vs baseline: 1.2261x; 1.1555x over previous
//
#include <hip/hip_runtime.h>

#define B 512
#define L 50
#define H 256
#define GN (B*L)          // 25600 graph nodes
#define GE (GN*12)        // 307200 edges

typedef unsigned short u16;
typedef unsigned int u32;
typedef __attribute__((ext_vector_type(8))) short short8;
typedef __attribute__((ext_vector_type(8))) unsigned short u16x8;
typedef __attribute__((ext_vector_type(4))) float f32x4;

__device__ __forceinline__ u16 f2bf(float f){ u32 x=__float_as_uint(f); u32 r=x+0x7FFFu+((x>>16)&1u); return (u16)(r>>16); }
__device__ __forceinline__ float waveSum(float v){
  #pragma unroll
  for (int m=32;m>0;m>>=1) v += __shfl_xor(v, m, 64);
  return v;
}
__device__ __forceinline__ float sigm(float x){ return 1.f/(1.f+expf(-x)); }

// fused: hidden = item_emb[items]; bf16 shadow; mi/mc means; gms, lend
__global__ void k_gather_means(const int* items, const int* cates, const int* mask,
                               const float* item_emb, const float* cate_emb,
                               float* hidden, u16* hiddenBf, float* mi, float* mc, float* gms, int* lend){
  int b=blockIdx.x, h=threadIdx.x;
  float si=0.f, sc=0.f, g=0.f; int lm=0;
  for (int l=0;l<L;l++){
    int it=items[b*L+l];
    float gm=(it>0)?1.f:((it<0)?-1.f:0.f);
    float v=item_emb[(size_t)it*H+h];
    hidden[((size_t)b*L+l)*H+h]=v;
    hiddenBf[((size_t)b*L+l)*H+h]=f2bf(v);
    si += gm*v;
    sc += gm*cate_emb[(size_t)cates[b*L+l]*H+h];
    g += gm;
    lm += mask[b*L+l];
  }
  mi[(size_t)b*H+h]=si/g; mc[(size_t)b*H+h]=sc/g;
  if (h==0){ gms[b]=g; lend[b]=lm; }
}

// seq_hidden = hidden[b,alias] + pos_emb + len_emb; bf16 shadow; ht row
__global__ void k_seq(const int* alias_, const int* mask, const float* hidden,
                      const float* pos_emb, const float* len_emb, const int* lend,
                      float* seqh, u16* seqBf, float* ht){
  int r=blockIdx.x, lane=threadIdx.x;
  int b=r/L, l=r%L;
  int a=alias_[r];
  int ld=lend[b];
  int m=mask[r];
  int pidx=(ld-1-l)*m;
  if (pidx<0) pidx+=L;               // jnp negative-index wrap
  float4 hv=*reinterpret_cast<const float4*>(hidden+((size_t)b*L+a)*H+lane*4);
  float4 pv=*reinterpret_cast<const float4*>(pos_emb+(size_t)pidx*H+lane*4);
  float4 lv=*reinterpret_cast<const float4*>(len_emb+(size_t)ld*H+lane*4);
  float4 o=make_float4(hv.x+pv.x+lv.x, hv.y+pv.y+lv.y, hv.z+pv.z+lv.z, hv.w+pv.w+lv.w);
  *reinterpret_cast<float4*>(seqh+(size_t)r*H+lane*4)=o;
  ushort4 ob=make_ushort4(f2bf(o.x),f2bf(o.y),f2bf(o.z),f2bf(o.w));
  *reinterpret_cast<ushort4*>(seqBf+(size_t)r*H+lane*4)=ob;
  if (l == (ld+L-1)%L)
    *reinterpret_cast<float4*>(ht+(size_t)b*H+lane*4)=o;
}

// WbfT[g][n][k] = bf16(Wsrc_g[k][n]) for the 3 big-GEMM weights
__global__ void k_prepW(const float* gat_W, const float* se_W, u16* WbfT){
  int n=blockIdx.x, g=blockIdx.y, k=threadIdx.x;
  const float* src = (g==0)? gat_W : (g==1? se_W+(size_t)2*H*H : se_W+(size_t)6*H*H);
  WbfT[((size_t)g*H+n)*H+k] = f2bf(src[(size_t)k*H+n]);
}

// C[M,256](f32) = Abf[M,256](bf16) @ WbfT[256n][256k](bf16, pre-transposed). MFMA 16x16x32.
__global__ __launch_bounds__(256) void k_gemm_mfma(const u16* Abf, const u16* WbfT,
                                                   float* C, int M){
  __shared__ u16 As[64][40];   // [m][k], 80B row stride: 16B-aligned, <=2-way banks
  __shared__ u16 Bs[64][40];   // [n][k]
  int bm=blockIdx.x*64, bn=blockIdx.y*64;
  int t=threadIdx.x, wv=t>>6, lane=t&63;
  int sr=t>>2, sk=(t&3)<<3;
  f32x4 acc[4]={};
  for (int k0=0;k0<H;k0+=32){
    u16x8 av=*reinterpret_cast<const u16x8*>(Abf+(size_t)(bm+sr)*H+k0+sk);
    u16x8 bv=*reinterpret_cast<const u16x8*>(WbfT+(size_t)(bn+sr)*H+k0+sk);
    *reinterpret_cast<u16x8*>(&As[sr][sk])=av;
    *reinterpret_cast<u16x8*>(&Bs[sr][sk])=bv;
    __syncthreads();
    int row=(wv<<4)+(lane&15);
    int ks=(lane>>4)<<3;
    short8 a=*reinterpret_cast<const short8*>(&As[row][ks]);
    #pragma unroll
    for (int ns=0;ns<4;ns++){
      short8 b=*reinterpret_cast<const short8*>(&Bs[(ns<<4)+(lane&15)][ks]);
      acc[ns]=__builtin_amdgcn_mfma_f32_16x16x32_bf16(a,b,acc[ns],0,0,0);
    }
    __syncthreads();
  }
  // C/D layout (m89-verified): col=lane&15, row=(lane>>4)*4+reg
  int r0=bm+(wv<<4)+((lane>>4)<<2);
  int c0=bn+(lane&15);
  #pragma unroll
  for (int ns=0;ns<4;ns++)
    #pragma unroll
    for (int i=0;i<4;i++)
      C[(size_t)(r0+i)*H + c0 + (ns<<4)] = acc[ns][i];
}

// C[M,Nc] = A[M,K] @ W[K,Nc] (+bias)  — f32 path for small/latency-bound GEMMs
__global__ __launch_bounds__(256) void k_gemm(const float* A, const float* W, size_t wOff,
                                              float* C, const float* bias, size_t bOff,
                                              int M, int Nc, int K){
  __shared__ float At[16][68];
  __shared__ float Ws[16][64];
  int bm=blockIdx.x*64, bn=blockIdx.y*64;
  int t=threadIdx.x;
  int tx=t&15, ty=t>>4;
  float c[4][4]={};
  int r=t>>2, kq=(t&3)<<2;
  int kk=t>>4, nq=(t&15)<<2;
  for (int k0=0;k0<K;k0+=16){
    float4 av=*reinterpret_cast<const float4*>(A+(size_t)(bm+r)*K+(k0+kq));
    At[kq+0][r]=av.x; At[kq+1][r]=av.y; At[kq+2][r]=av.z; At[kq+3][r]=av.w;
    float4 wv=*reinterpret_cast<const float4*>(W+wOff+(size_t)(k0+kk)*Nc+(bn+nq));
    Ws[kk][nq+0]=wv.x; Ws[kk][nq+1]=wv.y; Ws[kk][nq+2]=wv.z; Ws[kk][nq+3]=wv.w;
    __syncthreads();
    #pragma unroll
    for (int q=0;q<16;q++){
      float4 a4=*reinterpret_cast<const float4*>(&At[q][ty<<2]);
      float4 w4=*reinterpret_cast<const float4*>(&Ws[q][tx<<2]);
      float aa[4]={a4.x,a4.y,a4.z,a4.w};
      float ww[4]={w4.x,w4.y,w4.z,w4.w};
      #pragma unroll
      for (int i=0;i<4;i++)
        #pragma unroll
        for (int j=0;j<4;j++) c[i][j]=fmaf(aa[i],ww[j],c[i][j]);
    }
    __syncthreads();
  }
  #pragma unroll
  for (int i=0;i<4;i++){
    size_t row=(size_t)(bm+(ty<<2)+i);
    #pragma unroll
    for (int j=0;j<4;j++){
      int col=bn+(tx<<2)+j;
      float v=c[i][j];
      if (bias) v+=bias[bOff+col];
      C[row*Nc+col]=v;
    }
  }
}

// qb = A0@W[i0] + A1@W[i1] + A2@W[i2] + sum(4 bias rows)
__global__ __launch_bounds__(256) void k_qb3(const float* A0, const float* A1, const float* A2,
                                             const float* W, size_t wBase,
                                             const float* seb, size_t bOff, float* C){
  __shared__ float At[16][68];
  __shared__ float Ws[16][64];
  int bm=blockIdx.x*64, bn=blockIdx.y*64;
  int t=threadIdx.x;
  int tx=t&15, ty=t>>4;
  float c[4][4]={};
  int r=t>>2, kq=(t&3)<<2;
  int kk=t>>4, nq=(t&15)<<2;
  const float* As[3]={A0,A1,A2};
  const int widx[3]={0,1,3};
  for (int src=0;src<3;src++){
    const float* A=As[src];
    size_t wOff=wBase+(size_t)widx[src]*H*H;
    for (int k0=0;k0<H;k0+=16){
      float4 av=*reinterpret_cast<const float4*>(A+(size_t)(bm+r)*H+(k0+kq));
      At[kq+0][r]=av.x; At[kq+1][r]=av.y; At[kq+2][r]=av.z; At[kq+3][r]=av.w;
      float4 wv=*reinterpret_cast<const float4*>(W+wOff+(size_t)(k0+kk)*H+(bn+nq));
      Ws[kk][nq+0]=wv.x; Ws[kk][nq+1]=wv.y; Ws[kk][nq+2]=wv.z; Ws[kk][nq+3]=wv.w;
      __syncthreads();
      #pragma unroll
      for (int q=0;q<16;q++){
        float4 a4=*reinterpret_cast<const float4*>(&At[q][ty<<2]);
        float4 w4=*reinterpret_cast<const float4*>(&Ws[q][tx<<2]);
        float aa[4]={a4.x,a4.y,a4.z,a4.w};
        float ww[4]={w4.x,w4.y,w4.z,w4.w};
        #pragma unroll
        for (int i=0;i<4;i++)
          #pragma unroll
          for (int j=0;j<4;j++) c[i][j]=fmaf(aa[i],ww[j],c[i][j]);
      }
      __syncthreads();
    }
  }
  #pragma unroll
  for (int i=0;i<4;i++){
    size_t row=(size_t)(bm+(ty<<2)+i);
    #pragma unroll
    for (int j=0;j<4;j++){
      int col=bn+(tx<<2)+j;
      float v=c[i][j]
        + seb[bOff+0*H+col] + seb[bOff+1*H+col]
        + seb[bOff+2*H+col] + seb[bOff+3*H+col];
      C[row*H+col]=v;
    }
  }
}

// alpha[r] = sigmoid(qb[b]+q3[r]) . w5
__global__ void k_alpha(const float* qb, const float* q3, const float* w5, size_t wOff,
                        float* alpha){
  int gid=blockIdx.x*blockDim.x+threadIdx.x;
  int wid=gid>>6, lane=gid&63;
  if (wid>=GN) return;
  int b=wid/L;
  float4 qv=*reinterpret_cast<const float4*>(qb+(size_t)b*H+lane*4);
  float4 q3v=*reinterpret_cast<const float4*>(q3+(size_t)wid*H+lane*4);
  float4 wv=*reinterpret_cast<const float4*>(w5+wOff+(size_t)lane*4);
  float part = wv.x*sigm(qv.x+q3v.x) + wv.y*sigm(qv.y+q3v.y)
             + wv.z*sigm(qv.z+q3v.z) + wv.w*sigm(qv.w+q3v.w);
  part=waveSum(part);
  if (lane==0) alpha[wid]=part;
}

// a[b,h]=sum_l alpha*seq*mask ; cat=[a|ht]
__global__ void k_pool(const float* alpha, const float* seqh, const int* mask, const float* ht, float* cat){
  int b=blockIdx.x, h=threadIdx.x;
  float a=0.f;
  for (int l=0;l<L;l++)
    a += alpha[b*L+l]*seqh[((size_t)b*L+l)*H+h]*(float)mask[b*L+l];
  cat[(size_t)b*2*H+h]=a;
  cat[(size_t)b*2*H+H+h]=ht[(size_t)b*H+h];
}

__global__ void k_count(const int* dst, int* cnt){
  int e=blockIdx.x*blockDim.x+threadIdx.x;
  if (e<GE) atomicAdd(&cnt[dst[e]],1);
}

__global__ void k_scan(const int* cnt, int* rowp){
  __shared__ int s[1024];
  int t=threadIdx.x;
  int base=t*25;
  int local[25]; int sum=0;
  #pragma unroll
  for (int i=0;i<25;i++){ local[i]=sum; sum+=cnt[base+i]; }
  s[t]=sum; __syncthreads();
  for (int off=1;off<1024;off<<=1){
    int v=(t>=off)?s[t-off]:0; __syncthreads();
    s[t]+=v; __syncthreads();
  }
  int excl=s[t]-sum;
  #pragma unroll
  for (int i=0;i<25;i++) rowp[base+i]=excl+local[i];
  if (t==1023) rowp[GN]=s[1023];
}

__global__ void k_fill(const int* dst, const int* rowp, int* cnt, int* eord){
  int e=blockIdx.x*blockDim.x+threadIdx.x;
  if (e<GE){ int d=dst[e]; int pos=rowp[d]+atomicAdd(&cnt[d],1); eord[pos]=e; }
}

// one wave per node: online-softmax GAT aggregation
__global__ void k_node(const float* hg, const int* src, const int* etype, const float* eattr,
                       const float* rel, const int* rowp, const int* eord, float* out){
  int gid=blockIdx.x*blockDim.x+threadIdx.x;
  int n=gid>>6, lane=gid&63;
  if (n>=GN) return;
  float4 hn=*reinterpret_cast<const float4*>(hg+(size_t)n*H+lane*4);
  int b0=rowp[n], b1=rowp[n+1];
  float mx=-INFINITY, den=0.f;
  float4 acc=make_float4(0.f,0.f,0.f,0.f);
  for (int i=b0;i<b1;i++){
    int e=eord[i]; int s=src[e]; int ty=etype[e];
    float4 hs=*reinterpret_cast<const float4*>(hg+(size_t)s*H+lane*4);
    float4 rv=*reinterpret_cast<const float4*>(rel+(size_t)ty*H+lane*4);
    float4 m4=make_float4(hs.x+rv.x,hs.y+rv.y,hs.z+rv.z,hs.w+rv.w);
    float p=hn.x*m4.x+hn.y*m4.y+hn.z*m4.z+hn.w*m4.w;
    p=waveSum(p)*(1.f/16.f);
    float lg=(p>0.f?p:0.2f*p)+eattr[e];
    if (lg>mx){
      float sc=expf(mx-lg);
      den*=sc; acc.x*=sc; acc.y*=sc; acc.z*=sc; acc.w*=sc;
      mx=lg;
    }
    float ex=expf(lg-mx);
    den+=ex;
    acc.x+=ex*m4.x; acc.y+=ex*m4.y; acc.z+=ex*m4.z; acc.w+=ex*m4.w;
  }
  float inv=1.f/(den+1e-12f);
  float4 o=make_float4(acc.x*inv,acc.y*inv,acc.z*inv,acc.w*inv);
  *reinterpret_cast<float4*>(out+(size_t)n*H+lane*4)=o;
}

__global__ void k_avepool(const float* x, const int* items, const float* gms, float* out){
  int b=blockIdx.x, h=threadIdx.x;
  float s=0.f;
  for (int l=0;l<L;l++){
    int it=items[b*L+l];
    float gm=(it>0)?1.f:((it<0)?-1.f:0.f);
    s += gm*x[((size_t)b*L+l)*H+h];
  }
  out[(size_t)b*H+h]=s/gms[b];
}

// g_seq gather; bf16 shadow; ht_g row
__global__ void k_gseq(const int* alias_, const float* graph, const int* lend,
                       float* gseq, u16* gseqBf, float* ht){
  int r=blockIdx.x, lane=threadIdx.x;
  int b=r/L, l=r%L;
  int a=alias_[r];
  float4 v=*reinterpret_cast<const float4*>(graph+((size_t)b*L+a)*H+lane*4);
  *reinterpret_cast<float4*>(gseq+(size_t)r*H+lane*4)=v;
  ushort4 vb=make_ushort4(f2bf(v.x),f2bf(v.y),f2bf(v.z),f2bf(v.w));
  *reinterpret_cast<ushort4*>(gseqBf+(size_t)r*H+lane*4)=vb;
  int ld=lend[b];
  if (l == (ld+L-1)%L)
    *reinterpret_cast<float4*>(ht+(size_t)b*H+lane*4)=v;
}

// out = layer_norm(sl+sg); f32 out
__global__ void k_final(const float* sl, const float* sg, float* out){
  __shared__ float red[8];
  int b=blockIdx.x, h=threadIdx.x;
  int wid=h>>6, lane=h&63;
  float v=sl[(size_t)b*H+h]+sg[(size_t)b*H+h];
  float s=waveSum(v);
  if (lane==0) red[wid]=s;
  __syncthreads();
  float tot=red[0]+red[1]+red[2]+red[3];
  float x=v-tot/(float)H;
  float s2=waveSum(x*x);
  __syncthreads();
  if (lane==0) red[wid]=s2;
  __syncthreads();
  float ss=red[0]+red[1]+red[2]+red[3];
  out[(size_t)b*H+h]=x/sqrtf(ss);
}

extern "C" void kernel_launch(void* const* d_in, const int* in_sizes, int n_in,
                              void* d_out, int out_size, void* d_ws, size_t ws_size,
                              hipStream_t stream){
  (void)in_sizes; (void)n_in; (void)out_size; (void)ws_size;
  const int* alias_=(const int*)d_in[0];
  const int* items =(const int*)d_in[1];
  const int* mask  =(const int*)d_in[2];
  const int* cates =(const int*)d_in[3];
  const int* eind  =(const int*)d_in[4];
  const int* etype =(const int*)d_in[5];
  const float* eattr   =(const float*)d_in[6];
  const float* item_emb=(const float*)d_in[7];
  const float* cate_emb=(const float*)d_in[8];
  const float* pos_emb =(const float*)d_in[9];
  const float* len_emb =(const float*)d_in[10];
  const float* rel_emb =(const float*)d_in[11];
  const float* se_W    =(const float*)d_in[12];
  const float* se_b    =(const float*)d_in[13];
  const float* se_w5   =(const float*)d_in[14];
  const float* se_Wt   =(const float*)d_in[15];
  const float* se_bt   =(const float*)d_in[16];
  const float* gat_W   =(const float*)d_in[17];
  const int* esrc=eind; const int* edst=eind+GE;

  char* w=(char*)d_ws;
  auto carve=[&](size_t nbytes)->char*{ char* p=w; w += (nbytes+255)&~(size_t)255; return p; };
  float* buf1 =(float*)carve((size_t)GN*H*4);   // hidden, later graph_emb
  float* buf2 =(float*)carve((size_t)GN*H*4);   // seq_hidden, later g_seq
  float* hgat =(float*)carve((size_t)GN*H*4);
  float* q3   =(float*)carve((size_t)GN*H*4);
  u16*   hidBf=(u16*)  carve((size_t)GN*H*2);
  u16*   seqBf=(u16*)  carve((size_t)GN*H*2);
  u16*   gsqBf=(u16*)  carve((size_t)GN*H*2);
  u16*   wbfT =(u16*)  carve((size_t)3*H*H*2);
  float* alphaB=(float*)carve((size_t)GN*4);
  float* qb   =(float*)carve((size_t)B*H*4);
  float* mi   =(float*)carve((size_t)B*H*4);
  float* mc   =(float*)carve((size_t)B*H*4);
  float* sn   =(float*)carve((size_t)B*H*4);
  float* gms  =(float*)carve((size_t)B*4);
  int*   lend =(int*)  carve((size_t)B*4);
  float* htb  =(float*)carve((size_t)B*H*4);
  float* htg  =(float*)carve((size_t)B*H*4);
  float* catb =(float*)carve((size_t)B*2*H*4);
  float* sl   =(float*)carve((size_t)B*H*4);
  float* sg   =(float*)carve((size_t)B*H*4);
  int*   cnt  =(int*)  carve((size_t)GN*4);
  int*   rowp =(int*)  carve((size_t)(GN+1)*4);
  int*   eord =(int*)  carve((size_t)GE*4);

  dim3 blk(256), gSm(B/64,H/64), gM(GN/64,H/64), gPrep(H,3);

  k_prepW<<<gPrep,H,0,stream>>>(gat_W, se_W, wbfT);
  k_gather_means<<<B,256,0,stream>>>(items,cates,mask,item_emb,cate_emb,buf1,hidBf,mi,mc,gms,lend);
  k_seq<<<GN,64,0,stream>>>(alias_,mask,buf1,pos_emb,len_emb,lend,buf2,seqBf,htb);

  // GAT projection (MFMA bf16)
  k_gemm_mfma<<<gM,blk,0,stream>>>(hidBf, wbfT, hgat, GN);

  // local session encoder
  k_gemm_mfma<<<gM,blk,0,stream>>>(seqBf, wbfT+(size_t)1*H*H, q3, GN);
  k_qb3<<<gSm,blk,0,stream>>>(htb, mi, mc, se_W, 0, se_b, 0, qb);
  k_alpha<<<GN/4,256,0,stream>>>(qb,q3,se_w5,0,alphaB);
  k_pool<<<B,256,0,stream>>>(alphaB,buf2,mask,htb,catb);
  k_gemm<<<gSm,blk,0,stream>>>(catb, se_Wt, 0, sl, se_bt, 0, B,H,2*H);

  // GAT: CSR build + per-node online-softmax aggregation
  (void)hipMemsetAsync(cnt,0,(size_t)GN*4,stream);
  k_count<<<GE/256,256,0,stream>>>(edst,cnt);
  k_scan<<<1,1024,0,stream>>>(cnt,rowp);
  (void)hipMemsetAsync(cnt,0,(size_t)GN*4,stream);
  k_fill<<<GE/256,256,0,stream>>>(edst,rowp,cnt,eord);
  k_node<<<GN/4,256,0,stream>>>(hgat,esrc,etype,eattr,rel_emb,rowp,eord,buf1);

  // global session encoder
  k_avepool<<<B,256,0,stream>>>(buf1,items,gms,sn);
  k_gseq<<<GN,64,0,stream>>>(alias_,buf1,lend,buf2,gsqBf,htg);
  k_gemm_mfma<<<gM,blk,0,stream>>>(gsqBf, wbfT+(size_t)2*H*H, q3, GN);
  k_qb3<<<gSm,blk,0,stream>>>(htg, mi, sn, se_W, (size_t)4*H*H, se_b, (size_t)4*H, qb);
  k_alpha<<<GN/4,256,0,stream>>>(qb,q3,se_w5,(size_t)H,alphaB);
  k_pool<<<B,256,0,stream>>>(alphaB,buf2,mask,htg,catb);
  k_gemm<<<gSm,blk,0,stream>>>(catb, se_Wt, (size_t)2*H*H, sg, se_bt, (size_t)H, B,H,2*H);

  k_final<<<B,256,0,stream>>>(sl,sg,(float*)d_out);
}